// Round 6
// baseline (79.041 us; speedup 1.0000x reference)
//
#include <hip/hip_runtime.h>
#include <cfloat>

// x: (B=256, T=150, J=25, 3) fp32 -> out: (B, J, 9) fp32
// Per frame: pairwise dists among 25 joints; per joint the 4 smallest
// non-self distances d1<=d2<=d3<=d4 feed [avg,std(ddof=1),min] for
// k=2,3,4 (all three k come from the same sorted-4 prefix); mean over T.
#define NB 256
#define NT 150
#define NJ 25
#define CHUNK 2             // frames per wave (even, divides NT) -> max TLP
#define CPB (NT / CHUNK)    // 75 chunks per batch element
#define WAVES 4
#define BLOCKSZ 256
#define NW (NB * CPB)       // 19200 partial slots, 225 floats each -> 17.28 MB ws

// fast sqrt: direct v_sqrt_f32, no IEEE fixup (inputs are benign magnitudes)
#define FSQRT(x) __builtin_amdgcn_sqrtf(x)

// sorted ascending insert of v into (s0<=s1<=s2<=s3); only min kept at last step
#define INS4(s0, s1, s2, s3, v)                                   \
    {                                                             \
        float m_;                                                 \
        m_ = fminf(s0, v); v = fmaxf(s0, v); s0 = m_;             \
        m_ = fminf(s1, v); v = fmaxf(s1, v); s1 = m_;             \
        m_ = fminf(s2, v); v = fmaxf(s2, v); s2 = m_;             \
        s3 = fminf(s3, v);                                        \
    }

// __launch_bounds__(256,4): cap regalloc ~128 VGPR
__global__ __launch_bounds__(BLOCKSZ, 4) void knn_partial_kernel(
        const float* __restrict__ x, float* __restrict__ ws) {
    __shared__ float4 spos[WAVES][CHUNK][NJ];   // 3.2 KB/block

    const int tid  = threadIdx.x;
    const int wave = tid >> 6;
    const int lane = tid & 63;
    const int half = lane >> 5;     // which frame of the pair
    const int jj   = lane & 31;     // joint id within half
    const bool act = (jj < NJ);

    const int gw = blockIdx.x * WAVES + wave;   // [0, NW)
    const int b  = gw / CPB;
    const int c  = gw - b * CPB;
    const int t0 = c * CHUNK;

    // ---- stage the pair of frames (2 x 25 joints), packed -> padded float4 ----
    const float* src = x + (size_t)(b * NT + t0) * NJ * 3;
    for (int p = lane; p < CHUNK * NJ; p += 64) {
        const int f = p / NJ;
        const int j = p - f * NJ;
        const float* s = src + p * 3;
        spos[wave][f][j] = make_float4(s[0], s[1], s[2], 0.0f);
    }
    __syncthreads();   // single barrier; LDS read-only afterwards

    const float4 own = spos[wave][half][act ? jj : 0];

    // two parallel sorted-4 chains over SQUARED distances, candidates read
    // straight from LDS (2 broadcast addrs/wave -> conflict-free)
    float a0 = FLT_MAX, a1 = FLT_MAX, a2 = FLT_MAX, a3 = FLT_MAX;
    float e0 = FLT_MAX, e1 = FLT_MAX, e2 = FLT_MAX, e3 = FLT_MAX;
#pragma unroll
    for (int i = 0; i < 13; ++i) {
        const float4 q = spos[wave][half][i];
        const float dx = q.x - own.x, dy = q.y - own.y, dz = q.z - own.z;
        float d2 = dx * dx + dy * dy + dz * dz;
        d2 = (i == jj) ? FLT_MAX : d2;     // exclude self
        INS4(a0, a1, a2, a3, d2);
    }
#pragma unroll
    for (int i = 13; i < NJ; ++i) {
        const float4 q = spos[wave][half][i];
        const float dx = q.x - own.x, dy = q.y - own.y, dz = q.z - own.z;
        float d2 = dx * dx + dy * dy + dz * dz;
        d2 = (i == jj) ? FLT_MAX : d2;
        INS4(e0, e1, e2, e3, d2);
    }
    // bitonic merge: 4 smallest of (a ++ reverse(e)), then sort them
    const float l0 = fminf(a0, e3), l1 = fminf(a1, e2);
    const float l2 = fminf(a2, e1), l3 = fminf(a3, e0);
    const float m0 = fminf(l0, l2), m2 = fmaxf(l0, l2);
    const float m1 = fminf(l1, l3), m3 = fmaxf(l1, l3);
    const float r0 = fminf(m0, m1), r1 = fmaxf(m0, m1);
    const float r2 = fminf(m2, m3), r3 = fmaxf(m2, m3);

    const float d1 = FSQRT(r0), d2r = FSQRT(r1);
    const float d3 = FSQRT(r2), d4 = FSQRT(r3);

    // std via  var_k = (Sum d^2 - k*mean^2)/(k-1)  -- uses pre-sqrt r's
    const float rs2 = r0 + r1, rs3 = rs2 + r2, rs4 = rs3 + r3;
    float acc[9];
    // k=2
    const float s2 = d1 + d2r, a2f = 0.5f * s2;
    acc[0] = a2f;
    acc[1] = FSQRT(fmaxf(rs2 - 2.0f * a2f * a2f, 0.0f));
    acc[2] = d1;
    // k=3
    const float s3 = s2 + d3, a3f = s3 * (1.0f / 3.0f);
    acc[3] = a3f;
    acc[4] = FSQRT(fmaxf((rs3 - 3.0f * a3f * a3f) * 0.5f, 0.0f));
    acc[5] = d1;
    // k=4
    const float s4 = s3 + d4, a4f = 0.25f * s4;
    acc[6] = a4f;
    acc[7] = FSQRT(fmaxf((rs4 - 4.0f * a4f * a4f) * (1.0f / 3.0f), 0.0f));
    acc[8] = d1;

    // combine even/odd frame streams
#pragma unroll
    for (int f = 0; f < 9; ++f) acc[f] += __shfl_xor(acc[f], 32, 64);

    // plain coalesced partial store: ws[gw][f][j]
    if (act && half == 0) {
        float* op = ws + (size_t)gw * 225;
#pragma unroll
        for (int f = 0; f < 9; ++f) op[f * NJ + jj] = acc[f];
    }
}

__global__ __launch_bounds__(BLOCKSZ) void reduce_kernel(
        const float* __restrict__ ws, float* __restrict__ out) {
    const int i = blockIdx.x * blockDim.x + threadIdx.x;
    if (i >= NB * NJ * 9) return;
    const int b = i / 225;
    const int r = i - b * 225;
    float s = 0.0f;
#pragma unroll 5
    for (int c = 0; c < CPB; ++c) s += ws[(size_t)(b * CPB + c) * 225 + r];
    const int f = r / NJ;
    const int j = r - f * NJ;
    out[b * 225 + j * 9 + f] = s * (1.0f / (float)NT);
}

extern "C" void kernel_launch(void* const* d_in, const int* in_sizes, int n_in,
                              void* d_out, int out_size, void* d_ws, size_t ws_size,
                              hipStream_t stream) {
    const float* x = (const float*)d_in[0];
    float* out = (float*)d_out;
    float* ws = (float*)d_ws;   // NW * 225 floats = 17.28 MB

    knn_partial_kernel<<<NW / WAVES, BLOCKSZ, 0, stream>>>(x, ws);
    reduce_kernel<<<(NB * NJ * 9 + BLOCKSZ - 1) / BLOCKSZ, BLOCKSZ, 0, stream>>>(ws, out);
}

// Round 7
// 78.413 us; speedup vs baseline: 1.0080x; 1.0080x over previous
//
#include <hip/hip_runtime.h>
#include <cfloat>

// x: (B=256, T=150, J=25, 3) fp32 -> out: (B, J, 9) fp32
// Per frame: pairwise dists among 25 joints; per joint the 4 smallest
// non-self distances d1<=d2<=d3<=d4 feed [avg,std(ddof=1),min] for
// k=2,3,4 (all three k come from the same sorted-4 prefix); mean over T.
#define NB 256
#define NT 150
#define NJ 25
#define CHUNK 2             // frames per wave -> 19200 waves (18.75/SIMD feedable)
#define CPB (NT / CHUNK)    // 75 chunks per batch element
#define WAVES 4
#define BLOCKSZ 256
#define NW (NB * CPB)       // 19200 partial slots, 225 floats each -> 17.28 MB ws

// fast sqrt: direct v_sqrt_f32, no IEEE fixup (inputs are benign magnitudes)
#define FSQRT(x) __builtin_amdgcn_sqrtf(x)

// sorted ascending insert of v into (s0<=s1<=s2<=s3); only min kept at last step
#define INS4(s0, s1, s2, s3, v)                                   \
    {                                                             \
        float m_;                                                 \
        m_ = fminf(s0, v); v = fmaxf(s0, v); s0 = m_;             \
        m_ = fminf(s1, v); v = fmaxf(s1, v); s1 = m_;             \
        m_ = fminf(s2, v); v = fmaxf(s2, v); s2 = m_;             \
        s3 = fminf(s3, v);                                        \
    }

// (256, 8): min 8 waves/SIMD -> allocator targets <=64 VGPR; live set ~45, no spill
__global__ __launch_bounds__(BLOCKSZ, 8) void knn_partial_kernel(
        const float* __restrict__ x, float* __restrict__ ws) {
    __shared__ float4 spos[WAVES][CHUNK][NJ];   // 3.2 KB/block

    const int tid  = threadIdx.x;
    const int wave = tid >> 6;
    const int lane = tid & 63;
    const int half = lane >> 5;     // which frame of the pair
    const int jj   = lane & 31;     // joint id within half
    const bool act = (jj < NJ);

    const int gw = blockIdx.x * WAVES + wave;   // [0, NW)
    const int b  = gw / CPB;
    const int c  = gw - b * CPB;
    const int t0 = c * CHUNK;

    // ---- stage the frame pair: 50 joints, exactly one per lane<50 (no div) ----
    const float* src = x + (size_t)(b * NT + t0) * NJ * 3;
    if (lane < CHUNK * NJ) {
        const int f = (lane >= NJ) ? 1 : 0;
        const int j = lane - f * NJ;
        const float* s = src + lane * 3;
        spos[wave][f][j] = make_float4(s[0], s[1], s[2], 0.0f);
    }
    __syncthreads();   // single barrier; LDS read-only afterwards

    const float4 own = spos[wave][half][act ? jj : 0];

    // two parallel sorted-4 chains over SQUARED distances, candidates read
    // straight from LDS (2 broadcast addrs/wave -> conflict-free)
    float a0 = FLT_MAX, a1 = FLT_MAX, a2 = FLT_MAX, a3 = FLT_MAX;
    float e0 = FLT_MAX, e1 = FLT_MAX, e2 = FLT_MAX, e3 = FLT_MAX;
#pragma unroll
    for (int i = 0; i < 13; ++i) {
        const float4 q = spos[wave][half][i];
        const float dx = q.x - own.x, dy = q.y - own.y, dz = q.z - own.z;
        float d2 = dx * dx + dy * dy + dz * dz;
        d2 = (i == jj) ? FLT_MAX : d2;     // exclude self
        INS4(a0, a1, a2, a3, d2);
    }
#pragma unroll
    for (int i = 13; i < NJ; ++i) {
        const float4 q = spos[wave][half][i];
        const float dx = q.x - own.x, dy = q.y - own.y, dz = q.z - own.z;
        float d2 = dx * dx + dy * dy + dz * dz;
        d2 = (i == jj) ? FLT_MAX : d2;
        INS4(e0, e1, e2, e3, d2);
    }
    // bitonic merge: 4 smallest of (a ++ reverse(e)), then sort them
    const float l0 = fminf(a0, e3), l1 = fminf(a1, e2);
    const float l2 = fminf(a2, e1), l3 = fminf(a3, e0);
    const float m0 = fminf(l0, l2), m2 = fmaxf(l0, l2);
    const float m1 = fminf(l1, l3), m3 = fmaxf(l1, l3);
    const float r0 = fminf(m0, m1), r1 = fmaxf(m0, m1);
    const float r2 = fminf(m2, m3), r3 = fmaxf(m2, m3);

    float d1 = FSQRT(r0);
    const float d2r = FSQRT(r1), d3 = FSQRT(r2), d4 = FSQRT(r3);

    // std via  var_k = (Sum d^2 - k*mean^2)/(k-1)  -- uses pre-sqrt r's
    const float rs2 = r0 + r1, rs3 = rs2 + r2, rs4 = rs3 + r3;
    const float s2 = d1 + d2r;
    float a2f = 0.5f * s2;
    float sd2 = FSQRT(fmaxf(rs2 - 2.0f * a2f * a2f, 0.0f));
    const float s3 = s2 + d3;
    float a3f = s3 * (1.0f / 3.0f);
    float sd3 = FSQRT(fmaxf((rs3 - 3.0f * a3f * a3f) * 0.5f, 0.0f));
    const float s4 = s3 + d4;
    float a4f = 0.25f * s4;
    float sd4 = FSQRT(fmaxf((rs4 - 4.0f * a4f * a4f) * (1.0f / 3.0f), 0.0f));

    // combine even/odd frame streams (7 distinct values; min-feat is d1 for all k)
    a2f += __shfl_xor(a2f, 32, 64);
    sd2 += __shfl_xor(sd2, 32, 64);
    a3f += __shfl_xor(a3f, 32, 64);
    sd3 += __shfl_xor(sd3, 32, 64);
    a4f += __shfl_xor(a4f, 32, 64);
    sd4 += __shfl_xor(sd4, 32, 64);
    d1  += __shfl_xor(d1, 32, 64);

    // plain coalesced partial store: ws[gw][f][j]
    if (act && half == 0) {
        float* op = ws + (size_t)gw * 225;
        op[0 * NJ + jj] = a2f;
        op[1 * NJ + jj] = sd2;
        op[2 * NJ + jj] = d1;
        op[3 * NJ + jj] = a3f;
        op[4 * NJ + jj] = sd3;
        op[5 * NJ + jj] = d1;
        op[6 * NJ + jj] = a4f;
        op[7 * NJ + jj] = sd4;
        op[8 * NJ + jj] = d1;
    }
}

__global__ __launch_bounds__(BLOCKSZ) void reduce_kernel(
        const float* __restrict__ ws, float* __restrict__ out) {
    const int i = blockIdx.x * blockDim.x + threadIdx.x;
    if (i >= NB * NJ * 9) return;
    const int b = i / 225;
    const int r = i - b * 225;
    float s = 0.0f;
#pragma unroll 5
    for (int c = 0; c < CPB; ++c) s += ws[(size_t)(b * CPB + c) * 225 + r];
    const int f = r / NJ;
    const int j = r - f * NJ;
    out[b * 225 + j * 9 + f] = s * (1.0f / (float)NT);
}

extern "C" void kernel_launch(void* const* d_in, const int* in_sizes, int n_in,
                              void* d_out, int out_size, void* d_ws, size_t ws_size,
                              hipStream_t stream) {
    const float* x = (const float*)d_in[0];
    float* out = (float*)d_out;
    float* ws = (float*)d_ws;   // NW * 225 floats = 17.28 MB

    knn_partial_kernel<<<NW / WAVES, BLOCKSZ, 0, stream>>>(x, ws);
    reduce_kernel<<<(NB * NJ * 9 + BLOCKSZ - 1) / BLOCKSZ, BLOCKSZ, 0, stream>>>(ws, out);
}

// Round 9
// 74.273 us; speedup vs baseline: 1.0642x; 1.0557x over previous
//
#include <hip/hip_runtime.h>
#include <cfloat>

// x: (B=256, T=150, J=25, 3) fp32 -> out: (B, J, 9) fp32
// Per frame: pairwise dists among 25 joints; per joint the 4 smallest
// non-self distances d1<=d2<=d3<=d4 feed [avg,std(ddof=1),min] for
// k=2,3,4; mean over T.
//
// Decomposition: block = (b, half) -> 75 frames, 5 iters x 16 frame-slots.
// Within a wave: quarter (16 lanes) = one frame-slot; lane owns joint pair
// (2k, 2k+1). One ds_read_b128 of candidate i serves 4 frames x 2 joints.
#define NB 256
#define NT 150
#define NJ 25
#define HALF_T 75
#define SLOTS 16
#define ITERS 5             // ceil(75/16); slots 75..79 masked via vm
#define BLOCKSZ 256

#define FSQRT(x) __builtin_amdgcn_sqrtf(x)

// sorted ascending insert of v into (s0<=s1<=s2<=s3)
#define INS4(s0, s1, s2, s3, v)                                   \
    {                                                             \
        float m_;                                                 \
        m_ = fminf(s0, v); v = fmaxf(s0, v); s0 = m_;             \
        m_ = fminf(s1, v); v = fmaxf(s1, v); s1 = m_;             \
        m_ = fminf(s2, v); v = fmaxf(s2, v); s2 = m_;             \
        s3 = fminf(s3, v);                                        \
    }

// per-joint features from sorted squared dists r0..r3 -> f[7] = {a2,s2,a3,s3,a4,s4,d1}
__device__ __forceinline__ void features(float r0, float r1, float r2, float r3,
                                         float* f) {
    const float d1 = FSQRT(r0), d2 = FSQRT(r1), d3 = FSQRT(r2), d4 = FSQRT(r3);
    const float rs2 = r0 + r1, rs3 = rs2 + r2, rs4 = rs3 + r3;
    const float s2 = d1 + d2, a2f = 0.5f * s2;
    const float s3 = s2 + d3, a3f = s3 * (1.0f / 3.0f);
    const float s4 = s3 + d4, a4f = 0.25f * s4;
    f[0] = a2f;
    f[1] = FSQRT(fmaxf(rs2 - 2.0f * a2f * a2f, 0.0f));
    f[2] = a3f;
    f[3] = FSQRT(fmaxf((rs3 - 3.0f * a3f * a3f) * 0.5f, 0.0f));
    f[4] = a4f;
    f[5] = FSQRT(fmaxf((rs4 - 4.0f * a4f * a4f) * (1.0f / 3.0f), 0.0f));
    f[6] = d1;
}

__global__ __launch_bounds__(BLOCKSZ, 4) void knn_feat(
        const float* __restrict__ x, float* __restrict__ ws) {
    __shared__ float4 spos[SLOTS][NJ];     // 6.4 KB
    __shared__ float  red[4][16][14];      // 3.6 KB cross-wave reduce buffer

    const int tid  = threadIdx.x;
    const int wave = tid >> 6;
    const int lane = tid & 63;
    const int q    = (lane >> 4) & 3;      // quarter = frame-slot within wave
    const int k    = lane & 15;            // joint-pair owner
    const int slot = wave * 4 + q;         // 0..15
    const int jj0  = min(2 * k, NJ - 1);   // clamped pad joints; discarded at store
    const int jj1  = min(2 * k + 1, NJ - 1);

    const int blk = blockIdx.x;            // [0, 512)
    const int b   = blk >> 1;
    const int h   = blk & 1;
    const float* xb = x + (size_t)(b * NT + h * HALF_T) * NJ * 3;

    float acc0[7], acc1[7];
#pragma unroll
    for (int f = 0; f < 7; ++f) { acc0[f] = 0.0f; acc1[f] = 0.0f; }

#pragma unroll 1
    for (int it = 0; it < ITERS; ++it) {
        // ---- stage 16 frames (clamped at 74) packed float3 -> padded float4 ----
#pragma unroll
        for (int turn = 0; turn < 2; ++turn) {
            const int t = tid + turn * BLOCKSZ;
            if (t < SLOTS * NJ) {
                const int fl = t / NJ;             // frame slot local
                const int j  = t - fl * NJ;
                const int gf = min(it * SLOTS + fl, HALF_T - 1);
                const float* s = xb + (size_t)(gf * NJ + j) * 3;
                spos[fl][j] = make_float4(s[0], s[1], s[2], 0.0f);
            }
        }
        __syncthreads();

        const float4 own0 = spos[slot][jj0];
        const float4 own1 = spos[slot][jj1];

        // two serial sorted-4 chains (joint pair) over squared distances;
        // the 25 candidate reads are shared by 4 frames x 2 joints per wave
        float a0 = FLT_MAX, a1 = FLT_MAX, a2 = FLT_MAX, a3 = FLT_MAX;
        float e0 = FLT_MAX, e1 = FLT_MAX, e2 = FLT_MAX, e3 = FLT_MAX;
#pragma unroll
        for (int i = 0; i < NJ; ++i) {
            const float4 c = spos[slot][i];
            float dx = c.x - own0.x, dy = c.y - own0.y, dz = c.z - own0.z;
            float d20 = dx * dx + dy * dy + dz * dz;
            dx = c.x - own1.x; dy = c.y - own1.y; dz = c.z - own1.z;
            float d21 = dx * dx + dy * dy + dz * dz;
            d20 = (i == jj0) ? FLT_MAX : d20;      // exclude self
            d21 = (i == jj1) ? FLT_MAX : d21;
            INS4(a0, a1, a2, a3, d20);
            INS4(e0, e1, e2, e3, d21);
        }

        float f0[7], f1[7];
        features(a0, a1, a2, a3, f0);
        features(e0, e1, e2, e3, f1);

        // frame-validity mask (slots 75..79 in the last iter)
        const float vm = (it * SLOTS + slot < HALF_T) ? 1.0f : 0.0f;
#pragma unroll
        for (int f = 0; f < 7; ++f) {
            acc0[f] = fmaf(vm, f0[f], acc0[f]);
            acc1[f] = fmaf(vm, f1[f], acc1[f]);
        }
        __syncthreads();   // WAR before next stage
    }

    // ---- cross-quarter butterfly (same k across the 4 slots of this wave) ----
#pragma unroll
    for (int f = 0; f < 7; ++f) {
        acc0[f] += __shfl_xor(acc0[f], 16, 64);
        acc0[f] += __shfl_xor(acc0[f], 32, 64);
        acc1[f] += __shfl_xor(acc1[f], 16, 64);
        acc1[f] += __shfl_xor(acc1[f], 32, 64);
    }
    if (lane < 16) {
#pragma unroll
        for (int f = 0; f < 7; ++f) {
            red[wave][k][f]     = acc0[f];
            red[wave][k][7 + f] = acc1[f];
        }
    }
    __syncthreads();

    // ---- cross-wave sum + scaled partial store: ws[(b*2+h)][j][f7] ----
    if (tid < 16 * 14) {
        const int k2   = tid / 14;
        const int rest = tid - k2 * 14;
        const int which = rest / 7;
        const int f    = rest - which * 7;
        const int j    = 2 * k2 + which;
        if (j < NJ) {
            const float s = red[0][k2][rest] + red[1][k2][rest] +
                            red[2][k2][rest] + red[3][k2][rest];
            ws[(size_t)((b * 2 + h) * NJ + j) * 7 + f] = s * (1.0f / (float)NT);
        }
    }
}

// out[b][j][f9] = ws[b][0][j][f7] + ws[b][1][j][f7]
__global__ __launch_bounds__(BLOCKSZ) void final_kernel(
        const float* __restrict__ ws, float* __restrict__ out) {
    const int o = blockIdx.x * blockDim.x + threadIdx.x;
    if (o >= NB * NJ * 9) return;
    const int f9 = o % 9;
    const int bj = o / 9;          // b*25 + j
    const int j  = bj % NJ;
    const int b  = bj / NJ;
    const int f7 = (f9 % 3 == 2) ? 6 : (f9 / 3) * 2 + (f9 % 3);
    const size_t i0 = (size_t)((b * 2 + 0) * NJ + j) * 7 + f7;
    const size_t i1 = (size_t)((b * 2 + 1) * NJ + j) * 7 + f7;
    out[o] = ws[i0] + ws[i1];
}

extern "C" void kernel_launch(void* const* d_in, const int* in_sizes, int n_in,
                              void* d_out, int out_size, void* d_ws, size_t ws_size,
                              hipStream_t stream) {
    const float* x = (const float*)d_in[0];
    float* out = (float*)d_out;
    float* ws = (float*)d_ws;   // 512 * 175 floats = 358 KB

    knn_feat<<<NB * 2, BLOCKSZ, 0, stream>>>(x, ws);
    final_kernel<<<(NB * NJ * 9 + BLOCKSZ - 1) / BLOCKSZ, BLOCKSZ, 0, stream>>>(ws, out);
}

// Round 10
// 71.928 us; speedup vs baseline: 1.0989x; 1.0326x over previous
//
#include <hip/hip_runtime.h>
#include <cfloat>

// x: (B=256, T=150, J=25, 3) fp32 -> out: (B, J, 9) fp32
// Per frame: pairwise dists among 25 joints; per joint the 4 smallest
// non-self distances d1<=d2<=d3<=d4 feed [avg,std(ddof=1),min] for
// k=2,3,4; mean over T.
//
// Decomposition: block = (batch, tile of 15 frames) -> grid 2560 (10 blocks/CU,
// ~8 waves/SIMD). Wave quarter (16 lanes) = one frame-slot; lane owns joint
// pair (2k, 2k+1): one ds_read_b128 of candidate i serves 4 frames x 2 joints.
#define NB 256
#define NT 150
#define NJ 25
#define FPB 15              // frames per block
#define TILES (NT / FPB)    // 10
#define SLOTS 16            // frame slots (slot 15 = masked duplicate)
#define BLOCKSZ 256

#define FSQRT(x) __builtin_amdgcn_sqrtf(x)

// sorted ascending insert of v into (s0<=s1<=s2<=s3)
#define INS4(s0, s1, s2, s3, v)                                   \
    {                                                             \
        float m_;                                                 \
        m_ = fminf(s0, v); v = fmaxf(s0, v); s0 = m_;             \
        m_ = fminf(s1, v); v = fmaxf(s1, v); s1 = m_;             \
        m_ = fminf(s2, v); v = fmaxf(s2, v); s2 = m_;             \
        s3 = fminf(s3, v);                                        \
    }

// per-joint features from sorted squared dists r0..r3 -> f[7]={a2,s2,a3,s3,a4,s4,d1}
__device__ __forceinline__ void features(float r0, float r1, float r2, float r3,
                                         float* f) {
    const float d1 = FSQRT(r0), d2 = FSQRT(r1), d3 = FSQRT(r2), d4 = FSQRT(r3);
    const float rs2 = r0 + r1, rs3 = rs2 + r2, rs4 = rs3 + r3;
    const float s2 = d1 + d2, a2f = 0.5f * s2;
    const float s3 = s2 + d3, a3f = s3 * (1.0f / 3.0f);
    const float s4 = s3 + d4, a4f = 0.25f * s4;
    f[0] = a2f;
    f[1] = FSQRT(fmaxf(rs2 - 2.0f * a2f * a2f, 0.0f));
    f[2] = a3f;
    f[3] = FSQRT(fmaxf((rs3 - 3.0f * a3f * a3f) * 0.5f, 0.0f));
    f[4] = a4f;
    f[5] = FSQRT(fmaxf((rs4 - 4.0f * a4f * a4f) * (1.0f / 3.0f), 0.0f));
    f[6] = d1;
}

__global__ __launch_bounds__(BLOCKSZ, 8) void knn_feat(
        const float* __restrict__ x, float* __restrict__ ws) {
    __shared__ float4 spos[SLOTS][NJ];     // 6.4 KB
    __shared__ float  red[4][16][14];      // 3.5 KB cross-wave reduce buffer

    const int tid  = threadIdx.x;
    const int wave = tid >> 6;
    const int lane = tid & 63;
    const int q    = (lane >> 4) & 3;      // quarter = frame-slot within wave
    const int k    = lane & 15;            // joint-pair owner
    const int slot = wave * 4 + q;         // 0..15
    const int jj0  = min(2 * k, NJ - 1);   // clamped pad chains; dropped at store
    const int jj1  = min(2 * k + 1, NJ - 1);

    const int blk   = blockIdx.x;          // [0, 2560)
    const int batch = blk / TILES;
    const int tile  = blk - batch * TILES;
    const int t0    = tile * FPB;

    // ---- stage 16 frame-slots (slot 15 clamped to frame 149) ----
#pragma unroll
    for (int turn = 0; turn < 2; ++turn) {
        const int t = tid + turn * BLOCKSZ;
        if (t < SLOTS * NJ) {
            const int fl = t / NJ;
            const int j  = t - fl * NJ;
            const int gf = min(t0 + fl, NT - 1);
            const float* s = x + (size_t)((batch * NT + gf) * NJ + j) * 3;
            spos[fl][j] = make_float4(s[0], s[1], s[2], 0.0f);
        }
    }
    __syncthreads();

    const float4 own0 = spos[slot][jj0];
    const float4 own1 = spos[slot][jj1];

    // two interleaved sorted-4 chains (joint pair) over squared distances;
    // the 25 candidate reads are shared by 4 frames x 2 joints per wave
    float a0 = FLT_MAX, a1 = FLT_MAX, a2 = FLT_MAX, a3 = FLT_MAX;
    float e0 = FLT_MAX, e1 = FLT_MAX, e2 = FLT_MAX, e3 = FLT_MAX;
#pragma unroll
    for (int i = 0; i < NJ; ++i) {
        const float4 c = spos[slot][i];
        float dx = c.x - own0.x, dy = c.y - own0.y, dz = c.z - own0.z;
        float d20 = dx * dx + dy * dy + dz * dz;
        dx = c.x - own1.x; dy = c.y - own1.y; dz = c.z - own1.z;
        float d21 = dx * dx + dy * dy + dz * dz;
        d20 = (i == jj0) ? FLT_MAX : d20;      // exclude self
        d21 = (i == jj1) ? FLT_MAX : d21;
        INS4(a0, a1, a2, a3, d20);
        INS4(e0, e1, e2, e3, d21);
    }

    float f0[7], f1[7];
    features(a0, a1, a2, a3, f0);
    features(e0, e1, e2, e3, f1);

    // slot validity (slot 15 is a masked duplicate; values finite so 0*x safe)
    const float vm = (slot < FPB) ? 1.0f : 0.0f;
    float acc0[7], acc1[7];
#pragma unroll
    for (int f = 0; f < 7; ++f) {
        acc0[f] = vm * f0[f];
        acc1[f] = vm * f1[f];
    }

    // ---- cross-quarter butterfly (sums the wave's 4 frame-slots per k) ----
#pragma unroll
    for (int f = 0; f < 7; ++f) {
        acc0[f] += __shfl_xor(acc0[f], 16, 64);
        acc0[f] += __shfl_xor(acc0[f], 32, 64);
        acc1[f] += __shfl_xor(acc1[f], 16, 64);
        acc1[f] += __shfl_xor(acc1[f], 32, 64);
    }
    if (lane < 16) {
#pragma unroll
        for (int f = 0; f < 7; ++f) {
            red[wave][k][f]     = acc0[f];
            red[wave][k][7 + f] = acc1[f];
        }
    }
    __syncthreads();

    // ---- cross-wave sum + scaled partial store: ws[blk][j][f7] ----
    if (tid < 16 * 14) {
        const int k2    = tid / 14;
        const int rest  = tid - k2 * 14;
        const int which = rest / 7;
        const int f     = rest - which * 7;
        const int j     = 2 * k2 + which;
        if (j < NJ) {
            const float s = red[0][k2][rest] + red[1][k2][rest] +
                            red[2][k2][rest] + red[3][k2][rest];
            ws[(size_t)blk * 175 + j * 7 + f] = s * (1.0f / (float)NT);
        }
    }
}

// out[b][j][f9] = sum over 10 tiles of ws[b*10+tile][j][f7]
__global__ __launch_bounds__(BLOCKSZ) void final_kernel(
        const float* __restrict__ ws, float* __restrict__ out) {
    const int o = blockIdx.x * blockDim.x + threadIdx.x;
    if (o >= NB * NJ * 9) return;
    const int f9 = o % 9;
    const int bj = o / 9;          // b*25 + j
    const int j  = bj % NJ;
    const int b  = bj / NJ;
    const int f7 = (f9 % 3 == 2) ? 6 : (f9 / 3) * 2 + (f9 % 3);
    const float* p = ws + (size_t)b * TILES * 175 + j * 7 + f7;
    float s = 0.0f;
#pragma unroll
    for (int t = 0; t < TILES; ++t) s += p[t * 175];
    out[o] = s;
}

extern "C" void kernel_launch(void* const* d_in, const int* in_sizes, int n_in,
                              void* d_out, int out_size, void* d_ws, size_t ws_size,
                              hipStream_t stream) {
    const float* x = (const float*)d_in[0];
    float* out = (float*)d_out;
    float* ws = (float*)d_ws;   // 2560 * 175 floats = 1.75 MB

    knn_feat<<<NB * TILES, BLOCKSZ, 0, stream>>>(x, ws);
    final_kernel<<<(NB * NJ * 9 + BLOCKSZ - 1) / BLOCKSZ, BLOCKSZ, 0, stream>>>(ws, out);
}